// Round 5
// baseline (311.999 us; speedup 1.0000x reference)
//
#include <hip/hip_runtime.h>
#include <cstdint>
#include <cstddef>

#define B_  32
#define CIN 128
#define P_  256
#define E_  512
#define H_  64
#define W_  64
#define HO  32
#define WO  32

// ---------------- K1: merged bias GEMMs + weight prep ----------------
// bid < B_*160: bias rows (wave-per-row, silu inline)
// else: weight sf + bit-pack, 2 out-channels per block; zero stats accumulators
__global__ void k_bw(const float* __restrict__ emb,
                     const float* __restrict__ m1_w, const float* __restrict__ m1_b,
                     const float* __restrict__ m2_w, const float* __restrict__ m2_b,
                     const float* __restrict__ m3_w, const float* __restrict__ m3_b,
                     const float* __restrict__ conv_w,
                     float* __restrict__ b1, float* __restrict__ b2, float* __restrict__ b3,
                     float* __restrict__ sf, unsigned int* __restrict__ wbits,
                     float* __restrict__ s1, float* __restrict__ s2) {
    int bid = blockIdx.x;
    int tid = threadIdx.x;
    int wave = tid >> 6, lane = tid & 63;

    if (bid < B_ * 160) {
        // ---- bias path ----
        int n = bid / 160, rg = bid % 160;
        int row = rg * 4 + wave;         // 0..639
        const float* sp = emb + n * E_;
        const float* wrow; float bias; float* dst;
        if (row < CIN)            { wrow = m1_w + (size_t)row * E_;          bias = m1_b[row]; dst = b1 + n * CIN + row; }
        else if (row < CIN + P_)  { int c = row - CIN;      wrow = m2_w + (size_t)c * E_; bias = m2_b[c]; dst = b2 + n * P_ + c; }
        else                      { int c = row - CIN - P_; wrow = m3_w + (size_t)c * E_; bias = m3_b[c]; dst = b3 + n * P_ + c; }
        float acc = 0.f;
        #pragma unroll
        for (int j = 0; j < 8; j++) {
            int k = j * 64 + lane;
            float e = sp[k];
            acc += (e / (1.f + expf(-e))) * wrow[k];
        }
        #pragma unroll
        for (int off = 32; off > 0; off >>= 1) acc += __shfl_down(acc, off);
        if (lane == 0) *dst = acc + bias;
        return;
    }

    // ---- weight-prep path: oc pair ----
    int base = (bid - B_ * 160) * 2;
    int oc = base + (wave >> 1);
    int iw = wave & 1;                   // which 64-channel half
    int i  = iw * 64 + lane;             // input channel 0..127
    if (lane == 0 && iw == 0) { s1[oc] = 0.f; s2[oc] = 0.f; }
    const float* wp = conv_w + ((size_t)oc * CIN + i) * 9;
    float w[9]; float s = 0.f;
    #pragma unroll
    for (int t = 0; t < 9; t++) { w[t] = wp[t]; s += fabsf(w[t]); }
    #pragma unroll
    for (int t = 0; t < 9; t++) {
        unsigned long long m = __ballot(w[t] < 0.f);
        if (lane == 0) {
            wbits[oc * 36 + t * 4 + iw * 2 + 0] = (unsigned int)(m & 0xffffffffull);
            wbits[oc * 36 + t * 4 + iw * 2 + 1] = (unsigned int)(m >> 32);
        }
    }
    #pragma unroll
    for (int off = 32; off > 0; off >>= 1) s += __shfl_down(s, off);
    __shared__ float sred[4];
    if (lane == 0) sred[wave] = s;
    __syncthreads();
    if (tid == 0)        sf[base]     = (sred[0] + sred[1]) / 1152.f;
    else if (tid == 128) sf[base + 1] = (sred[2] + sred[3]) / 1152.f;
}

// ---------------- K2: fused sign(x+b1) bit-pack + 2x2 avgpool (single pass over x) ----------------
// grid: bid = n*32 + h2 (pool row). Block covers x rows {2*h2, 2*h2+1}, all 128 ch.
__global__ void k_prep(const float* __restrict__ x, const float* __restrict__ b1,
                       unsigned int* __restrict__ abits, float* __restrict__ xpool) {
    __shared__ float sb1[CIN];
    int n = blockIdx.x >> 5, h2 = blockIdx.x & 31;
    int tid = threadIdx.x;
    for (int i = tid; i < CIN; i += 256) sb1[i] = b1[n * CIN + i];
    __syncthreads();

    // part A: abits. thread -> (pixel = tid>>1 of the 2x64 row-pair, half = tid&1 -> 64 channels)
    int pix = tid >> 1, half = tid & 1;
    int h = 2 * h2 + (pix >> 6), w = pix & 63;
    const float* xp = x + ((size_t)n * CIN + half * 64) * (H_ * W_) + (size_t)h * W_ + w;
    unsigned int wds[2];
    #pragma unroll
    for (int wd = 0; wd < 2; wd++) {
        unsigned int m = 0;
        #pragma unroll
        for (int b = 0; b < 32; b++) {
            float v = xp[(size_t)(wd * 32 + b) * (H_ * W_)] + sb1[half * 64 + wd * 32 + b];
            m |= (v < 0.f ? 1u : 0u) << b;
        }
        wds[wd] = m;
    }
    ((uint2*)abits)[((size_t)n * 4096 + (size_t)h * 64 + w) * 2 + half] = make_uint2(wds[0], wds[1]);

    // part B: avgpool from the same (L2-resident) rows
    for (int idx = tid; idx < CIN * WO; idx += 256) {
        int c = idx >> 5, w2 = idx & 31;
        const float* p = x + ((size_t)n * CIN + c) * (H_ * W_) + (size_t)(2 * h2) * W_ + 2 * w2;
        float2 a = *(const float2*)p;
        float2 b = *(const float2*)(p + W_);
        xpool[((size_t)n * CIN + c) * (HO * WO) + h2 * WO + w2] = 0.25f * (a.x + a.y + b.x + b.y);
    }
}

// ---------------- K3: conv pass 1 -> BN stats only (no y write) ----------------
// bid = n*32 + ocg*4 + strip. 1024 independent blocks, 4/CU.
__global__ void __launch_bounds__(256, 4) k_cstat(const unsigned int* __restrict__ abits,
                                                  const unsigned int* __restrict__ wbits,
                                                  const float* __restrict__ sf,
                                                  float* __restrict__ s1, float* __restrict__ s2) {
    __shared__ __align__(16) uint4 swb[32 * 9];
    __shared__ float red1[32][33], red2[32][33];   // padded: conflict-free column reads
    int bid = blockIdx.x;
    int strip = bid & 3, ocg = (bid >> 2) & 7, n = bid >> 5;
    int tid = threadIdx.x;
    int wave = tid >> 6, lane = tid & 63;
    int oh = strip * 8 + (tid >> 5), ow = tid & 31;

    const uint4* wsrc = ((const uint4*)wbits) + (size_t)ocg * 32 * 9;
    for (int i = tid; i < 32 * 9; i += 256) swb[i] = wsrc[i];

    const uint4* asrc = ((const uint4*)abits) + ((size_t)n << 12);
    uint4 img[9]; int vmask = 0;
    #pragma unroll
    for (int kh = 0; kh < 3; kh++) {
        #pragma unroll
        for (int kw = 0; kw < 3; kw++) {
            int t = kh * 3 + kw;
            int r = 2 * oh - 1 + kh, c = 2 * ow - 1 + kw;
            bool v = (unsigned)r < 64u && (unsigned)c < 64u;
            img[t] = v ? asrc[r * 64 + c] : make_uint4(0u, 0u, 0u, 0u);
            vmask |= (v ? 1 : 0) << t;
        }
    }
    int base128 = 128 * __popc(vmask);
    __syncthreads();

    const float* sfp = sf + ocg * 32;
    #pragma unroll 4
    for (int o = 0; o < 32; o++) {
        int popsum = 0;
        #pragma unroll
        for (int t = 0; t < 9; t++) {
            uint4 a = img[t];
            uint4 w = swb[o * 9 + t];
            int p = __popc(a.x ^ w.x) + __popc(a.y ^ w.y) +
                    __popc(a.z ^ w.z) + __popc(a.w ^ w.w);
            popsum += ((vmask >> t) & 1) ? p : 0;
        }
        float v = sfp[o] * (float)(base128 - 2 * popsum);
        float vs = v, v2 = v * v;
        vs += __shfl_down(vs, 32); v2 += __shfl_down(v2, 32);
        vs += __shfl_down(vs, 16); v2 += __shfl_down(v2, 16);
        vs += __shfl_down(vs, 8);  v2 += __shfl_down(v2, 8);
        if (lane < 8) { red1[o][wave * 8 + lane] = vs; red2[o][wave * 8 + lane] = v2; }
    }
    __syncthreads();
    if (tid < 64) {
        int o = tid & 31;
        float a = 0.f;
        if (tid < 32) {
            #pragma unroll
            for (int p = 0; p < 32; p++) a += red1[o][p];
            atomicAdd(s1 + ocg * 32 + o, a);
        } else {
            #pragma unroll
            for (int p = 0; p < 32; p++) a += red2[o][p];
            atomicAdd(s2 + ocg * 32 + o, a);
        }
    }
}

// ---------------- K4: conv pass 2 (recompute) + BN apply + skip + bias2 + PReLU + bias3 ----------------
__global__ void __launch_bounds__(256, 4) k_cepi(const unsigned int* __restrict__ abits,
                                                 const unsigned int* __restrict__ wbits,
                                                 const float* __restrict__ sf,
                                                 const float* __restrict__ s1, const float* __restrict__ s2,
                                                 const float* __restrict__ bn_g, const float* __restrict__ bn_b,
                                                 const float* __restrict__ b2, const float* __restrict__ b3,
                                                 const float* __restrict__ prelu_a,
                                                 const float* __restrict__ xpool,
                                                 float* __restrict__ y) {
    __shared__ __align__(16) uint4 swb[32 * 9];
    __shared__ float Lm[32], Lr[32], La[32], Ladd[32], Lb3[32];
    int bid = blockIdx.x;
    int strip = bid & 3, ocg = (bid >> 2) & 7, n = bid >> 5;
    int tid = threadIdx.x;
    int oh = strip * 8 + (tid >> 5), ow = tid & 31;

    const uint4* wsrc = ((const uint4*)wbits) + (size_t)ocg * 32 * 9;
    for (int i = tid; i < 32 * 9; i += 256) swb[i] = wsrc[i];
    if (tid < 32) {
        int c = ocg * 32 + tid;
        const float inv = 1.f / (B_ * HO * WO);
        float m = s1[c] * inv;
        float var = fmaf(-m, m, s2[c] * inv);
        float r = rsqrtf(var + 1e-5f) * bn_g[c];
        Lm[tid] = m; Lr[tid] = r;
        La[tid] = prelu_a[c];
        Ladd[tid] = bn_b[c] + b2[n * P_ + c];
        Lb3[tid] = b3[n * P_ + c];
    }

    const uint4* asrc = ((const uint4*)abits) + ((size_t)n << 12);
    uint4 img[9]; int vmask = 0;
    #pragma unroll
    for (int kh = 0; kh < 3; kh++) {
        #pragma unroll
        for (int kw = 0; kw < 3; kw++) {
            int t = kh * 3 + kw;
            int r = 2 * oh - 1 + kh, c = 2 * ow - 1 + kw;
            bool v = (unsigned)r < 64u && (unsigned)c < 64u;
            img[t] = v ? asrc[r * 64 + c] : make_uint4(0u, 0u, 0u, 0u);
            vmask |= (v ? 1 : 0) << t;
        }
    }
    int base128 = 128 * __popc(vmask);
    __syncthreads();

    int pix = strip * 256 + tid;
    const float* xpb = xpool + (((size_t)n * CIN + (ocg & 3) * 32) << 10) + pix;
    float* yp = y + (((size_t)n * P_ + ocg * 32) << 10) + pix;
    const float* sfp = sf + ocg * 32;
    #pragma unroll 4
    for (int o = 0; o < 32; o++) {
        int popsum = 0;
        #pragma unroll
        for (int t = 0; t < 9; t++) {
            uint4 a = img[t];
            uint4 w = swb[o * 9 + t];
            int p = __popc(a.x ^ w.x) + __popc(a.y ^ w.y) +
                    __popc(a.z ^ w.z) + __popc(a.w ^ w.w);
            popsum += ((vmask >> t) & 1) ? p : 0;
        }
        float v = sfp[o] * (float)(base128 - 2 * popsum);
        float vv = (v - Lm[o]) * Lr[o] + Ladd[o] + xpb[(size_t)o << 10];
        vv = vv > 0.f ? vv : La[o] * vv;
        yp[(size_t)o << 10] = vv + Lb3[o];
    }
}

extern "C" void kernel_launch(void* const* d_in, const int* in_sizes, int n_in,
                              void* d_out, int out_size, void* d_ws, size_t ws_size,
                              hipStream_t stream) {
    const float* x      = (const float*)d_in[0];
    const float* emb    = (const float*)d_in[1];
    const float* m1_w   = (const float*)d_in[2];
    const float* m1_b   = (const float*)d_in[3];
    const float* conv_w = (const float*)d_in[4];
    // d_in[5] = conv_b : cancels exactly under training-mode BN, unused
    const float* bn_g   = (const float*)d_in[6];
    const float* bn_b   = (const float*)d_in[7];
    const float* m2_w   = (const float*)d_in[8];
    const float* m2_b   = (const float*)d_in[9];
    const float* prelu_a= (const float*)d_in[10];
    const float* m3_w   = (const float*)d_in[11];
    const float* m3_b   = (const float*)d_in[12];

    float* y = (float*)d_out;

    // workspace carve-up (f32 words)
    float* wsf = (float*)d_ws;
    float* b1    = wsf;                  // 32*128
    float* b2    = wsf + 4096;           // 32*256
    float* b3    = wsf + 12288;          // 32*256
    float* sf    = wsf + 20480;          // 256
    float* s1    = wsf + 20736;          // 256  (zeroed by k_bw)
    float* s2    = wsf + 20992;          // 256  (zeroed by k_bw)
    unsigned int* wbits = (unsigned int*)(wsf + 21248);   // 256*36 u32
    unsigned int* abits = (unsigned int*)(wsf + 30464);   // 32*64*64*4 u32 (2 MiB)
    float* xpool = wsf + 554752;         // 32*128*32*32 f32 (16 MiB)

    k_bw   <<<B_ * 160 + P_ / 2, 256, 0, stream>>>(emb, m1_w, m1_b, m2_w, m2_b, m3_w, m3_b,
                                                   conv_w, b1, b2, b3, sf, wbits, s1, s2);
    k_prep <<<B_ * 32, 256, 0, stream>>>(x, b1, abits, xpool);
    k_cstat<<<B_ * 32, 256, 0, stream>>>(abits, wbits, sf, s1, s2);
    k_cepi <<<B_ * 32, 256, 0, stream>>>(abits, wbits, sf, s1, s2,
                                         bn_g, bn_b, b2, b3, prelu_a, xpool, y);
}

// Round 6
// 195.205 us; speedup vs baseline: 1.5983x; 1.5983x over previous
//
#include <hip/hip_runtime.h>
#include <cstdint>
#include <cstddef>

#define B_  32
#define CIN 128
#define P_  256
#define E_  512
#define H_  64
#define W_  64
#define HO  32
#define WO  32

// ---------------- K1: merged bias GEMMs + weight prep ----------------
// bid < B_*160: bias rows (wave-per-row, silu inline)
// else: weight sf + bit-pack, 2 out-channels per block; zero stats accumulators
__global__ void k_bw(const float* __restrict__ emb,
                     const float* __restrict__ m1_w, const float* __restrict__ m1_b,
                     const float* __restrict__ m2_w, const float* __restrict__ m2_b,
                     const float* __restrict__ m3_w, const float* __restrict__ m3_b,
                     const float* __restrict__ conv_w,
                     float* __restrict__ b1, float* __restrict__ b2, float* __restrict__ b3,
                     float* __restrict__ sf, unsigned int* __restrict__ wbits,
                     float* __restrict__ s1, float* __restrict__ s2) {
    int bid = blockIdx.x;
    int tid = threadIdx.x;
    int wave = tid >> 6, lane = tid & 63;

    if (bid < B_ * 160) {
        // ---- bias path ----
        int n = bid / 160, rg = bid % 160;
        int row = rg * 4 + wave;         // 0..639
        const float* sp = emb + n * E_;
        const float* wrow; float bias; float* dst;
        if (row < CIN)            { wrow = m1_w + (size_t)row * E_;          bias = m1_b[row]; dst = b1 + n * CIN + row; }
        else if (row < CIN + P_)  { int c = row - CIN;      wrow = m2_w + (size_t)c * E_; bias = m2_b[c]; dst = b2 + n * P_ + c; }
        else                      { int c = row - CIN - P_; wrow = m3_w + (size_t)c * E_; bias = m3_b[c]; dst = b3 + n * P_ + c; }
        float acc = 0.f;
        #pragma unroll
        for (int j = 0; j < 8; j++) {
            int k = j * 64 + lane;
            float e = sp[k];
            acc += (e / (1.f + expf(-e))) * wrow[k];
        }
        #pragma unroll
        for (int off = 32; off > 0; off >>= 1) acc += __shfl_down(acc, off);
        if (lane == 0) *dst = acc + bias;
        return;
    }

    // ---- weight-prep path: oc pair ----
    int base = (bid - B_ * 160) * 2;
    int oc = base + (wave >> 1);
    int iw = wave & 1;                   // which 64-channel half
    int i  = iw * 64 + lane;             // input channel 0..127
    if (lane == 0 && iw == 0) { s1[oc] = 0.f; s2[oc] = 0.f; }
    const float* wp = conv_w + ((size_t)oc * CIN + i) * 9;
    float w[9]; float s = 0.f;
    #pragma unroll
    for (int t = 0; t < 9; t++) { w[t] = wp[t]; s += fabsf(w[t]); }
    #pragma unroll
    for (int t = 0; t < 9; t++) {
        unsigned long long m = __ballot(w[t] < 0.f);
        if (lane == 0) {
            wbits[oc * 36 + t * 4 + iw * 2 + 0] = (unsigned int)(m & 0xffffffffull);
            wbits[oc * 36 + t * 4 + iw * 2 + 1] = (unsigned int)(m >> 32);
        }
    }
    #pragma unroll
    for (int off = 32; off > 0; off >>= 1) s += __shfl_down(s, off);
    __shared__ float sred[4];
    if (lane == 0) sred[wave] = s;
    __syncthreads();
    if (tid == 0)        sf[base]     = (sred[0] + sred[1]) / 1152.f;
    else if (tid == 128) sf[base + 1] = (sred[2] + sred[3]) / 1152.f;
}

// ---------------- K2: fused sign(x+b1) bit-pack + 2x2 avgpool (single pass over x) ----------------
// grid: bid = n*32 + h2 (pool row). Block covers x rows {2*h2, 2*h2+1}, all 128 ch.
__global__ void k_prep(const float* __restrict__ x, const float* __restrict__ b1,
                       unsigned int* __restrict__ abits, float* __restrict__ xpool) {
    __shared__ float sb1[CIN];
    int n = blockIdx.x >> 5, h2 = blockIdx.x & 31;
    int tid = threadIdx.x;
    for (int i = tid; i < CIN; i += 256) sb1[i] = b1[n * CIN + i];
    __syncthreads();

    // part A: abits. thread -> (pixel = tid>>1 of the 2x64 row-pair, half = tid&1 -> 64 channels)
    int pix = tid >> 1, half = tid & 1;
    int h = 2 * h2 + (pix >> 6), w = pix & 63;
    const float* xp = x + ((size_t)n * CIN + half * 64) * (H_ * W_) + (size_t)h * W_ + w;
    unsigned int wds[2];
    #pragma unroll
    for (int wd = 0; wd < 2; wd++) {
        unsigned int m = 0;
        #pragma unroll
        for (int b = 0; b < 32; b++) {
            float v = xp[(size_t)(wd * 32 + b) * (H_ * W_)] + sb1[half * 64 + wd * 32 + b];
            m |= (v < 0.f ? 1u : 0u) << b;
        }
        wds[wd] = m;
    }
    ((uint2*)abits)[((size_t)n * 4096 + (size_t)h * 64 + w) * 2 + half] = make_uint2(wds[0], wds[1]);

    // part B: avgpool from the same (L2-resident) rows
    for (int idx = tid; idx < CIN * WO; idx += 256) {
        int c = idx >> 5, w2 = idx & 31;
        const float* p = x + ((size_t)n * CIN + c) * (H_ * W_) + (size_t)(2 * h2) * W_ + 2 * w2;
        float2 a = *(const float2*)p;
        float2 b = *(const float2*)(p + W_);
        xpool[((size_t)n * CIN + c) * (HO * WO) + h2 * WO + w2] = 0.25f * (a.x + a.y + b.x + b.y);
    }
}

// ---------------- K3: XNOR conv, weights via wave-uniform scalar loads (no LDS at all) ----------------
// bid = n*32 + ocg*4 + strip. Writes pre-BN y.
__global__ void __launch_bounds__(256, 4) k_conv(const unsigned int* __restrict__ abits,
                                                 const unsigned int* __restrict__ wbits,
                                                 const float* __restrict__ sf,
                                                 float* __restrict__ y) {
    int bid = blockIdx.x;
    int strip = bid & 3, ocg = (bid >> 2) & 7, n = bid >> 5;
    int tid = threadIdx.x;
    int oh = strip * 8 + (tid >> 5), ow = tid & 31;

    // 9 image taps into VGPRs (abits 2 MB -> L2-resident)
    const uint4* asrc = ((const uint4*)abits) + ((size_t)n << 12);
    uint4 img[9]; int vmask = 0;
    #pragma unroll
    for (int kh = 0; kh < 3; kh++) {
        #pragma unroll
        for (int kw = 0; kw < 3; kw++) {
            int t = kh * 3 + kw;
            int r = 2 * oh - 1 + kh, c = 2 * ow - 1 + kw;
            bool v = (unsigned)r < 64u && (unsigned)c < 64u;
            img[t] = v ? asrc[r * 64 + c] : make_uint4(0u, 0u, 0u, 0u);
            vmask |= (v ? 1 : 0) << t;
        }
    }
    int base128 = 128 * __popc(vmask);

    // weights: block-uniform address -> compiler emits s_load_dwordx4 into SGPRs;
    // v_xor_b32 reads the SGPR operand directly. Zero LDS traffic in the hot loop.
    const uint4* wp = ((const uint4*)wbits) + (size_t)ocg * 32 * 9;
    const float* sfp = sf + ocg * 32;
    float* yp = y + (((size_t)n * P_ + ocg * 32) << 10) + strip * 256 + tid;
    #pragma unroll 4
    for (int o = 0; o < 32; o++) {
        int popsum = 0;
        #pragma unroll
        for (int t = 0; t < 9; t++) {
            uint4 a = img[t];
            uint4 w = wp[o * 9 + t];                  // uniform -> scalar load
            int p = __popc(a.x ^ w.x) + __popc(a.y ^ w.y) +
                    __popc(a.z ^ w.z) + __popc(a.w ^ w.w);
            popsum += ((vmask >> t) & 1) ? p : 0;
        }
        yp[(size_t)o << 10] = sfp[o] * (float)(base128 - 2 * popsum);
    }
}

// ---------------- K4: BN partial sums (per channel), float4 reads (R2-proven) ----------------
__global__ void k_stats(const float* __restrict__ y,
                        float* __restrict__ s1, float* __restrict__ s2) {
    int c = blockIdx.x >> 2, q = blockIdx.x & 3;   // quarter of the batch
    int tid = threadIdx.x;
    float s = 0.f, ss = 0.f;
    for (int n = q * 8; n < q * 8 + 8; n++) {
        float4 v = ((const float4*)y)[(((size_t)n * P_ + c) << 8) + tid];
        s  += v.x + v.y + v.z + v.w;
        ss += v.x * v.x + v.y * v.y + v.z * v.z + v.w * v.w;
    }
    #pragma unroll
    for (int off = 32; off > 0; off >>= 1) {
        s += __shfl_down(s, off); ss += __shfl_down(ss, off);
    }
    __shared__ float r1[4], r2[4];
    int wave = tid >> 6, lane = tid & 63;
    if (lane == 0) { r1[wave] = s; r2[wave] = ss; }
    __syncthreads();
    if (tid == 0) {
        atomicAdd(s1 + c, r1[0] + r1[1] + r1[2] + r1[3]);
        atomicAdd(s2 + c, r2[0] + r2[1] + r2[2] + r2[3]);
    }
}

// ---------------- K5: BN finalize+apply + skip + bias2 + PReLU + bias3, float4 (R2-proven) ----------------
__global__ void k_epi(float* __restrict__ y, const float* __restrict__ xpool,
                      const float* __restrict__ s1, const float* __restrict__ s2,
                      const float* __restrict__ bn_g, const float* __restrict__ bn_b,
                      const float* __restrict__ b2, const float* __restrict__ b3,
                      const float* __restrict__ prelu_a) {
    int i4 = blockIdx.x * blockDim.x + threadIdx.x;   // float4 index
    int pix4 = i4 & 255;
    int c = (i4 >> 8) & 255;
    int n = i4 >> 16;
    float4 yv = ((const float4*)y)[i4];
    float4 xv = ((const float4*)xpool)[((n * CIN + (c & 127)) << 8) + pix4];
    const float inv = 1.f / (B_ * HO * WO);
    float m = s1[c] * inv;
    float var = fmaf(-m, m, s2[c] * inv);
    float r = rsqrtf(var + 1e-5f) * bn_g[c];
    float add0 = bn_b[c] + b2[n * P_ + c];
    float a = prelu_a[c];
    float b3v = b3[n * P_ + c];
    float o0 = (yv.x - m) * r + add0 + xv.x; o0 = (o0 > 0.f ? o0 : a * o0) + b3v;
    float o1 = (yv.y - m) * r + add0 + xv.y; o1 = (o1 > 0.f ? o1 : a * o1) + b3v;
    float o2 = (yv.z - m) * r + add0 + xv.z; o2 = (o2 > 0.f ? o2 : a * o2) + b3v;
    float o3 = (yv.w - m) * r + add0 + xv.w; o3 = (o3 > 0.f ? o3 : a * o3) + b3v;
    ((float4*)y)[i4] = make_float4(o0, o1, o2, o3);
}

extern "C" void kernel_launch(void* const* d_in, const int* in_sizes, int n_in,
                              void* d_out, int out_size, void* d_ws, size_t ws_size,
                              hipStream_t stream) {
    const float* x      = (const float*)d_in[0];
    const float* emb    = (const float*)d_in[1];
    const float* m1_w   = (const float*)d_in[2];
    const float* m1_b   = (const float*)d_in[3];
    const float* conv_w = (const float*)d_in[4];
    // d_in[5] = conv_b : cancels exactly under training-mode BN, unused
    const float* bn_g   = (const float*)d_in[6];
    const float* bn_b   = (const float*)d_in[7];
    const float* m2_w   = (const float*)d_in[8];
    const float* m2_b   = (const float*)d_in[9];
    const float* prelu_a= (const float*)d_in[10];
    const float* m3_w   = (const float*)d_in[11];
    const float* m3_b   = (const float*)d_in[12];

    float* y = (float*)d_out;   // pre-BN buffer, finalized in-place by k_epi

    // workspace carve-up (f32 words)
    float* wsf = (float*)d_ws;
    float* b1    = wsf;                  // 32*128
    float* b2    = wsf + 4096;           // 32*256
    float* b3    = wsf + 12288;          // 32*256
    float* sf    = wsf + 20480;          // 256
    float* s1    = wsf + 20736;          // 256  (zeroed by k_bw)
    float* s2    = wsf + 20992;          // 256  (zeroed by k_bw)
    unsigned int* wbits = (unsigned int*)(wsf + 21248);   // 256*36 u32
    unsigned int* abits = (unsigned int*)(wsf + 30464);   // 32*64*64*4 u32 (2 MiB)
    float* xpool = wsf + 554752;         // 32*128*32*32 f32 (16 MiB)

    k_bw   <<<B_ * 160 + P_ / 2, 256, 0, stream>>>(emb, m1_w, m1_b, m2_w, m2_b, m3_w, m3_b,
                                                   conv_w, b1, b2, b3, sf, wbits, s1, s2);
    k_prep <<<B_ * 32, 256, 0, stream>>>(x, b1, abits, xpool);
    k_conv <<<B_ * 32, 256, 0, stream>>>(abits, wbits, sf, y);
    k_stats<<<P_ * 4, 256, 0, stream>>>(y, s1, s2);
    k_epi  <<<(B_ * P_ * HO * WO) / (4 * 256), 256, 0, stream>>>(y, xpool, s1, s2,
                                                                 bn_g, bn_b, b2, b3, prelu_a);
}

// Round 7
// 190.376 us; speedup vs baseline: 1.6389x; 1.0254x over previous
//
#include <hip/hip_runtime.h>
#include <cstdint>
#include <cstddef>

#define B_  32
#define CIN 128
#define P_  256
#define E_  512
#define H_  64
#define W_  64
#define HO  32
#define WO  32

// ---------------- K1: merged bias GEMMs + weight prep (R6-proven) ----------------
__global__ void k_bw(const float* __restrict__ emb,
                     const float* __restrict__ m1_w, const float* __restrict__ m1_b,
                     const float* __restrict__ m2_w, const float* __restrict__ m2_b,
                     const float* __restrict__ m3_w, const float* __restrict__ m3_b,
                     const float* __restrict__ conv_w,
                     float* __restrict__ b1, float* __restrict__ b2, float* __restrict__ b3,
                     float* __restrict__ sf, unsigned int* __restrict__ wbits,
                     float* __restrict__ s1, float* __restrict__ s2) {
    int bid = blockIdx.x;
    int tid = threadIdx.x;
    int wave = tid >> 6, lane = tid & 63;

    if (bid < B_ * 160) {
        // ---- bias path: wave-per-row, silu inline ----
        int n = bid / 160, rg = bid % 160;
        int row = rg * 4 + wave;         // 0..639
        const float* sp = emb + n * E_;
        const float* wrow; float bias; float* dst;
        if (row < CIN)            { wrow = m1_w + (size_t)row * E_;          bias = m1_b[row]; dst = b1 + n * CIN + row; }
        else if (row < CIN + P_)  { int c = row - CIN;      wrow = m2_w + (size_t)c * E_; bias = m2_b[c]; dst = b2 + n * P_ + c; }
        else                      { int c = row - CIN - P_; wrow = m3_w + (size_t)c * E_; bias = m3_b[c]; dst = b3 + n * P_ + c; }
        float acc = 0.f;
        #pragma unroll
        for (int j = 0; j < 8; j++) {
            int k = j * 64 + lane;
            float e = sp[k];
            acc += (e / (1.f + expf(-e))) * wrow[k];
        }
        #pragma unroll
        for (int off = 32; off > 0; off >>= 1) acc += __shfl_down(acc, off);
        if (lane == 0) *dst = acc + bias;
        return;
    }

    // ---- weight-prep path: 2 out-channels per block ----
    int base = (bid - B_ * 160) * 2;
    int oc = base + (wave >> 1);
    int iw = wave & 1;                   // which 64-channel half
    int i  = iw * 64 + lane;             // input channel 0..127
    if (lane == 0 && iw == 0) { s1[oc] = 0.f; s2[oc] = 0.f; }
    const float* wp = conv_w + ((size_t)oc * CIN + i) * 9;
    float w[9]; float s = 0.f;
    #pragma unroll
    for (int t = 0; t < 9; t++) { w[t] = wp[t]; s += fabsf(w[t]); }
    #pragma unroll
    for (int t = 0; t < 9; t++) {
        unsigned long long m = __ballot(w[t] < 0.f);
        if (lane == 0) {
            wbits[oc * 36 + t * 4 + iw * 2 + 0] = (unsigned int)(m & 0xffffffffull);
            wbits[oc * 36 + t * 4 + iw * 2 + 1] = (unsigned int)(m >> 32);
        }
    }
    #pragma unroll
    for (int off = 32; off > 0; off >>= 1) s += __shfl_down(s, off);
    __shared__ float sred[4];
    if (lane == 0) sred[wave] = s;
    __syncthreads();
    if (tid == 0)        sf[base]     = (sred[0] + sred[1]) / 1152.f;
    else if (tid == 128) sf[base + 1] = (sred[2] + sred[3]) / 1152.f;
}

// ---------------- K2: fused sign(x+b1) bit-pack + 2x2 avgpool (R6-proven) ----------------
__global__ void k_prep(const float* __restrict__ x, const float* __restrict__ b1,
                       unsigned int* __restrict__ abits, float* __restrict__ xpool) {
    __shared__ float sb1[CIN];
    int n = blockIdx.x >> 5, h2 = blockIdx.x & 31;
    int tid = threadIdx.x;
    for (int i = tid; i < CIN; i += 256) sb1[i] = b1[n * CIN + i];
    __syncthreads();

    int pix = tid >> 1, half = tid & 1;
    int h = 2 * h2 + (pix >> 6), w = pix & 63;
    const float* xp = x + ((size_t)n * CIN + half * 64) * (H_ * W_) + (size_t)h * W_ + w;
    unsigned int wds[2];
    #pragma unroll
    for (int wd = 0; wd < 2; wd++) {
        unsigned int m = 0;
        #pragma unroll
        for (int b = 0; b < 32; b++) {
            float v = xp[(size_t)(wd * 32 + b) * (H_ * W_)] + sb1[half * 64 + wd * 32 + b];
            m |= (v < 0.f ? 1u : 0u) << b;
        }
        wds[wd] = m;
    }
    ((uint2*)abits)[((size_t)n * 4096 + (size_t)h * 64 + w) * 2 + half] = make_uint2(wds[0], wds[1]);

    for (int idx = tid; idx < CIN * WO; idx += 256) {
        int c = idx >> 5, w2 = idx & 31;
        const float* p = x + ((size_t)n * CIN + c) * (H_ * W_) + (size_t)(2 * h2) * W_ + 2 * w2;
        float2 a = *(const float2*)p;
        float2 b = *(const float2*)(p + W_);
        xpool[((size_t)n * CIN + c) * (HO * WO) + h2 * WO + w2] = 0.25f * (a.x + a.y + b.x + b.y);
    }
}

// ---------------- K3: XNOR conv (SGPR weights) -> int16 y + fused BN int stats ----------------
// bid = n*32 + ocg*4 + strip. Writes s = base128 - 2*popsum as int16; accumulates
// per-channel integer partial sums (exact) into float atomics.
__global__ void __launch_bounds__(256, 4) k_convstat(const unsigned int* __restrict__ abits,
                                                     const unsigned int* __restrict__ wbits,
                                                     short* __restrict__ y16,
                                                     float* __restrict__ s1, float* __restrict__ s2) {
    __shared__ int red1[32][33], red2[32][33];   // padded: conflict-free
    int bid = blockIdx.x;
    int strip = bid & 3, ocg = (bid >> 2) & 7, n = bid >> 5;
    int tid = threadIdx.x;
    int wave = tid >> 6, lane = tid & 63;
    int oh = strip * 8 + (tid >> 5), ow = tid & 31;

    // 9 image taps into VGPRs (abits 2 MB -> L2-resident)
    const uint4* asrc = ((const uint4*)abits) + ((size_t)n << 12);
    uint4 img[9]; int vmask = 0;
    #pragma unroll
    for (int kh = 0; kh < 3; kh++) {
        #pragma unroll
        for (int kw = 0; kw < 3; kw++) {
            int t = kh * 3 + kw;
            int r = 2 * oh - 1 + kh, c = 2 * ow - 1 + kw;
            bool v = (unsigned)r < 64u && (unsigned)c < 64u;
            img[t] = v ? asrc[r * 64 + c] : make_uint4(0u, 0u, 0u, 0u);
            vmask |= (v ? 1 : 0) << t;
        }
    }
    int base128 = 128 * __popc(vmask);

    // weights via wave-uniform scalar loads (no LDS in hot loop)
    const uint4* wp = ((const uint4*)wbits) + (size_t)ocg * 32 * 9;
    short* yp = y16 + (((size_t)n * P_ + ocg * 32) << 10) + strip * 256 + tid;
    #pragma unroll 4
    for (int o = 0; o < 32; o++) {
        int popsum = 0;
        #pragma unroll
        for (int t = 0; t < 9; t++) {
            uint4 a = img[t];
            uint4 w = wp[o * 9 + t];
            int p = __popc(a.x ^ w.x) + __popc(a.y ^ w.y) +
                    __popc(a.z ^ w.z) + __popc(a.w ^ w.w);
            popsum += ((vmask >> t) & 1) ? p : 0;
        }
        int s = base128 - 2 * popsum;             // [-1152, 1152]
        yp[(size_t)o << 10] = (short)s;
        int vs = s, v2 = s * s;
        vs += __shfl_down(vs, 32); v2 += __shfl_down(v2, 32);
        vs += __shfl_down(vs, 16); v2 += __shfl_down(v2, 16);
        vs += __shfl_down(vs, 8);  v2 += __shfl_down(v2, 8);
        if (lane < 8) { red1[o][wave * 8 + lane] = vs; red2[o][wave * 8 + lane] = v2; }
    }
    __syncthreads();
    if (tid < 64) {
        int o = tid & 31;
        int a = 0;
        if (tid < 32) {
            #pragma unroll
            for (int p = 0; p < 32; p++) a += red1[o][p];
            atomicAdd(s1 + ocg * 32 + o, (float)a);
        } else {
            #pragma unroll
            for (int p = 0; p < 32; p++) a += red2[o][p];
            atomicAdd(s2 + ocg * 32 + o, (float)a);   // <= 1.36e9, fits int32 exactly pre-cast
        }
    }
}

// ---------------- K4: BN finalize+apply + skip + bias2 + PReLU + bias3 -> d_out ----------------
__global__ void k_epi(const short* __restrict__ y16, const float* __restrict__ xpool,
                      const float* __restrict__ sf,
                      const float* __restrict__ s1, const float* __restrict__ s2,
                      const float* __restrict__ bn_g, const float* __restrict__ bn_b,
                      const float* __restrict__ b2, const float* __restrict__ b3,
                      const float* __restrict__ prelu_a, float* __restrict__ out) {
    int i4 = blockIdx.x * blockDim.x + threadIdx.x;   // 4-pixel index
    int pix4 = i4 & 255;
    int c = (i4 >> 8) & 255;
    int n = i4 >> 16;
    short4 yv = ((const short4*)y16)[i4];
    float4 xv = ((const float4*)xpool)[((n * CIN + (c & 127)) << 8) + pix4];
    const float inv = 1.f / (B_ * HO * WO);
    float sc = sf[c];
    float m = sc * s1[c] * inv;                          // mean of sf*s
    float var = fmaf(-m, m, sc * sc * s2[c] * inv);      // E[(sf*s)^2] - mean^2
    float r = rsqrtf(var + 1e-5f) * bn_g[c];
    float add0 = bn_b[c] + b2[n * P_ + c];
    float a = prelu_a[c];
    float b3v = b3[n * P_ + c];
    float o0 = (sc * (float)yv.x - m) * r + add0 + xv.x; o0 = (o0 > 0.f ? o0 : a * o0) + b3v;
    float o1 = (sc * (float)yv.y - m) * r + add0 + xv.y; o1 = (o1 > 0.f ? o1 : a * o1) + b3v;
    float o2 = (sc * (float)yv.z - m) * r + add0 + xv.z; o2 = (o2 > 0.f ? o2 : a * o2) + b3v;
    float o3 = (sc * (float)yv.w - m) * r + add0 + xv.w; o3 = (o3 > 0.f ? o3 : a * o3) + b3v;
    ((float4*)out)[i4] = make_float4(o0, o1, o2, o3);
}

extern "C" void kernel_launch(void* const* d_in, const int* in_sizes, int n_in,
                              void* d_out, int out_size, void* d_ws, size_t ws_size,
                              hipStream_t stream) {
    const float* x      = (const float*)d_in[0];
    const float* emb    = (const float*)d_in[1];
    const float* m1_w   = (const float*)d_in[2];
    const float* m1_b   = (const float*)d_in[3];
    const float* conv_w = (const float*)d_in[4];
    // d_in[5] = conv_b : cancels exactly under training-mode BN, unused
    const float* bn_g   = (const float*)d_in[6];
    const float* bn_b   = (const float*)d_in[7];
    const float* m2_w   = (const float*)d_in[8];
    const float* m2_b   = (const float*)d_in[9];
    const float* prelu_a= (const float*)d_in[10];
    const float* m3_w   = (const float*)d_in[11];
    const float* m3_b   = (const float*)d_in[12];

    float* out = (float*)d_out;   // written once, by k_epi

    // workspace carve-up (f32 words)
    float* wsf = (float*)d_ws;
    float* b1    = wsf;                  // 32*128
    float* b2    = wsf + 4096;           // 32*256
    float* b3    = wsf + 12288;          // 32*256
    float* sf    = wsf + 20480;          // 256
    float* s1    = wsf + 20736;          // 256  (zeroed by k_bw)
    float* s2    = wsf + 20992;          // 256  (zeroed by k_bw)
    unsigned int* wbits = (unsigned int*)(wsf + 21248);   // 256*36 u32
    unsigned int* abits = (unsigned int*)(wsf + 30464);   // 32*64*64*4 u32 (2 MiB)
    float* xpool = wsf + 554752;         // 32*128*32*32 f32 (16 MiB)
    short* y16   = (short*)(wsf + 4749056 + 16384);       // 32*256*1024 i16 (16 MiB)

    k_bw      <<<B_ * 160 + P_ / 2, 256, 0, stream>>>(emb, m1_w, m1_b, m2_w, m2_b, m3_w, m3_b,
                                                      conv_w, b1, b2, b3, sf, wbits, s1, s2);
    k_prep    <<<B_ * 32, 256, 0, stream>>>(x, b1, abits, xpool);
    k_convstat<<<B_ * 32, 256, 0, stream>>>(abits, wbits, y16, s1, s2);
    k_epi     <<<(B_ * P_ * HO * WO) / (4 * 256), 256, 0, stream>>>(y16, xpool, sf, s1, s2,
                                                                    bn_g, bn_b, b2, b3, prelu_a, out);
}